// Round 12
// baseline (379.424 us; speedup 1.0000x reference)
//
#include <hip/hip_runtime.h>
#include <hip/hip_bf16.h>
#include <stdint.h>

// Problem constants
#define Bq 1024
#define Dq 512
#define Nq 16
#define Hq 512
#define Mq (Bq*Nq)   // 16384

typedef short v8s  __attribute__((ext_vector_type(8)));
typedef float v4f  __attribute__((ext_vector_type(4)));

typedef __attribute__((address_space(3))) unsigned int as3_u32;
typedef __attribute__((address_space(1))) const unsigned int as1_u32;

__device__ __forceinline__ unsigned short f2bf(float f) {
  union { float f; unsigned u; } v; v.f = f;
  return (unsigned short)((v.u + 0x7fffu + ((v.u >> 16) & 1u)) >> 16);
}

// Merged prep: blocks [0,1024) transpose x; blocks [1024, 1024+18*256)
// transpose the 18 weight matrices.
__global__ void k_prep(const float* __restrict__ x,
                       const float* __restrict__ Ws1, const float* __restrict__ Ws2,
                       const float* __restrict__ Wc1,
                       unsigned short* __restrict__ xb,
                       unsigned short* __restrict__ Ws1t, unsigned short* __restrict__ Ws2t,
                       unsigned short* __restrict__ Wc1t) {
  const int bid = blockIdx.x;
  const int t = threadIdx.x;
  if (bid < Bq) {
    __shared__ float lds[Dq][Nq + 1];
    const float* xi = x + (size_t)bid * Dq * Nq;
    for (int p = 0; p < (Dq*Nq)/256; ++p) {
      int i = t + p*256;
      lds[i >> 4][i & (Nq-1)] = xi[i];
    }
    __syncthreads();
    unsigned short* o = xb + (size_t)bid * Nq * Dq;
    for (int p = 0; p < (Dq*Nq)/256; ++p) {
      int i = t + p*256;
      o[i] = f2bf(lds[i & (Dq-1)][i >> 9]);   // i = n*512 + d
    }
  } else {
    __shared__ float tile[32][33];
    const int r = bid - Bq;
    const int z = r >> 8;
    const int rem = r & 255;
    const int bx = rem & 15, by = rem >> 4;
    const float* in;
    unsigned short* out;
    if (z == 0)      { in = Ws1; out = Ws1t; }
    else if (z == 1) { in = Ws2; out = Ws2t; }
    else             { in = Wc1 + (size_t)(z-2) * 512 * 512; out = Wc1t + (size_t)(z-2) * 512 * 512; }
    const int tx = t & 31, ty = t >> 5;
    const int c0 = bx * 32, r0 = by * 32;
#pragma unroll
    for (int j = 0; j < 4; ++j)
      tile[ty + j*8][tx] = in[(size_t)(r0 + ty + j*8) * 512 + c0 + tx];
    __syncthreads();
#pragma unroll
    for (int j = 0; j < 4; ++j) {
      int c = c0 + ty + j*8;
      int rr = r0 + tx;
      out[(size_t)c * 512 + rr] = f2bf(tile[tx][ty + j*8]);
    }
  }
}

// ---------------------------------------------------------------------------
// Shared-MLP GEMM (R10, passed): 128x256 tile, 4 waves of 64x128, 16x16x32
// fragments, zero-conflict chunk-XOR swizzle, BK=32 dbuf.
// ---------------------------------------------------------------------------
__global__ __launch_bounds__(256, 2)
void k_gemm2(const unsigned short* __restrict__ A,
             const unsigned short* __restrict__ Bt,
             const float* __restrict__ bias,
             unsigned short* __restrict__ O,
             int permute) {
  __shared__ __align__(16) unsigned short As[2][128][32];
  __shared__ __align__(16) unsigned short Bs[2][256][32];

  const int t = threadIdx.x;
  const int wave = t >> 6, lane = t & 63;
  const int wr = wave >> 1, wc = wave & 1;
  const int fr = lane & 15, fq = lane >> 4;

  const int bm = blockIdx.x * 128;
  const int bn = blockIdx.y * 256;

  const int sr = lane >> 2;
  const int sc = (lane & 3) ^ ((sr >> 1) & 3);
  const unsigned short* aSrc = A  + (size_t)(bm + wave*32 + sr) * Dq + sc*8;
  const unsigned short* bSrc = Bt + (size_t)(bn + wave*64 + sr) * Dq + sc*8;

  auto stage = [&](int buf, int kt) {
#pragma unroll
    for (int j = 0; j < 2; ++j)
      __builtin_amdgcn_global_load_lds((as1_u32*)(aSrc + kt*32 + (size_t)j*16*Dq),
                                       (as3_u32*)&As[buf][wave*32 + j*16][0], 16, 0, 0);
#pragma unroll
    for (int j = 0; j < 4; ++j)
      __builtin_amdgcn_global_load_lds((as1_u32*)(bSrc + kt*32 + (size_t)j*16*Dq),
                                       (as3_u32*)&Bs[buf][wave*64 + j*16][0], 16, 0, 0);
  };

  const int swz = (fq ^ ((fr >> 1) & 3)) * 16;
  int offA[4], offB[8];
#pragma unroll
  for (int mi = 0; mi < 4; ++mi) offA[mi] = (wr*64  + mi*16 + fr) * 64 + swz;
#pragma unroll
  for (int ni = 0; ni < 8; ++ni) offB[ni] = (wc*128 + ni*16 + fr) * 64 + swz;

  v4f acc[4][8] = {};

  stage(0, 0);
  __syncthreads();

  for (int kt = 0; kt < 16; ++kt) {
    const int cur = kt & 1;
    if (kt + 1 < 16) stage(cur ^ 1, kt + 1);

    const char* aB = (const char*)&As[cur][0][0];
    const char* bB = (const char*)&Bs[cur][0][0];
    v8s af[4], bf[8];
#pragma unroll
    for (int mi = 0; mi < 4; ++mi) af[mi] = *(const v8s*)(aB + offA[mi]);
#pragma unroll
    for (int ni = 0; ni < 8; ++ni) bf[ni] = *(const v8s*)(bB + offB[ni]);
#pragma unroll
    for (int mi = 0; mi < 4; ++mi)
#pragma unroll
      for (int ni = 0; ni < 8; ++ni)
        acc[mi][ni] = __builtin_amdgcn_mfma_f32_16x16x32_bf16(af[mi], bf[ni], acc[mi][ni], 0, 0, 0);

    __syncthreads();
  }

  float bcol[8];
#pragma unroll
  for (int ni = 0; ni < 8; ++ni) bcol[ni] = bias[bn + wc*128 + ni*16 + fr];
#pragma unroll
  for (int mi = 0; mi < 4; ++mi) {
#pragma unroll
    for (int reg = 0; reg < 4; ++reg) {
      int grow = bm + wr*64 + mi*16 + fq*4 + reg;
      int orow = permute ? ((grow & 15) * Bq + (grow >> 4)) : grow;
#pragma unroll
      for (int ni = 0; ni < 8; ++ni) {
        int col = bn + wc*128 + ni*16 + fr;
        float v = acc[mi][ni][reg] + bcol[ni];
        v = v >= 0.f ? v : 0.1f * v;
        O[(size_t)orow * 512 + col] = f2bf(v);
      }
    }
  }
}

// ---------------------------------------------------------------------------
// Head-GEMM v12: BK=64 + double-buffering (the untested cell in the proven
// family).  128x128 tile, 4 waves of 64x64, 16x16x32 fragments on 128-B rows
// with the R5-verified zero-conflict swizzle (chunk ^ (row&7)).  8 K-steps
// (vs 16): the ~650-cyc constant per-step gap (R8 vs R9 evidence) is paid
// half as often; dbuf keeps the prefetch cover.  LDS 64 KiB -> 2 blocks/CU.
// Epilogue accumulates into per-bn partial slices FL2[bn][m][z] (atomics only
// between the 2 col-half waves of the same block + same-slice blocks: 128x
// less contention than a single FL).
// ---------------------------------------------------------------------------
__global__ __launch_bounds__(256, 2)
void k_headgemm(const unsigned short* __restrict__ A,
                const unsigned short* __restrict__ Bt,
                const float* __restrict__ bias,
                float* __restrict__ FL2,
                const float* __restrict__ w2) {
  __shared__ __align__(16) unsigned short As[2][128][64];
  __shared__ __align__(16) unsigned short Bs[2][128][64];

  const int t = threadIdx.x;
  const int wave = t >> 6, lane = t & 63;
  const int wr = wave >> 1, wc = wave & 1;
  const int fr = lane & 15, fq = lane >> 4;

  const int bm = blockIdx.x * 128;
  const int bn = blockIdx.y * 128;
  const int z  = blockIdx.z;

  const unsigned short* Bz = Bt + (size_t)z * Dq * 512;
  const float* biasz = bias + (size_t)z * 512;
  const float* w2z   = w2   + (size_t)z * 512;

  const int sr8 = lane >> 3;
  const int sc8 = (lane & 7) ^ sr8;
  const unsigned short* aSrc = A  + (size_t)(bm + wave*32 + sr8) * Dq + sc8*8;
  const unsigned short* bSrc = Bz + (size_t)(bn + wave*32 + sr8) * Dq + sc8*8;

  auto stage = [&](int buf, int kt) {
#pragma unroll
    for (int g = 0; g < 4; ++g)
      __builtin_amdgcn_global_load_lds((as1_u32*)(aSrc + kt*64 + (size_t)g*8*Dq),
                                       (as3_u32*)&As[buf][wave*32 + g*8][0], 16, 0, 0);
#pragma unroll
    for (int g = 0; g < 4; ++g)
      __builtin_amdgcn_global_load_lds((as1_u32*)(bSrc + kt*64 + (size_t)g*8*Dq),
                                       (as3_u32*)&Bs[buf][wave*32 + g*8][0], 16, 0, 0);
  };

  int offA[4][2], offB[4][2];
#pragma unroll
  for (int mi = 0; mi < 4; ++mi) {
    int r = wr*64 + mi*16 + fr;
#pragma unroll
    for (int kh = 0; kh < 2; ++kh)
      offA[mi][kh] = r*128 + (((kh*4 + fq) ^ (fr & 7)) * 16);
  }
#pragma unroll
  for (int ni = 0; ni < 4; ++ni) {
    int r = wc*64 + ni*16 + fr;
#pragma unroll
    for (int kh = 0; kh < 2; ++kh)
      offB[ni][kh] = r*128 + (((kh*4 + fq) ^ (fr & 7)) * 16);
  }

  v4f acc[4][4] = {};

  stage(0, 0);
  __syncthreads();

  for (int kt = 0; kt < 8; ++kt) {
    const int cur = kt & 1;
    if (kt + 1 < 8) stage(cur ^ 1, kt + 1);

    const char* aB = (const char*)&As[cur][0][0];
    const char* bB = (const char*)&Bs[cur][0][0];
#pragma unroll
    for (int kh = 0; kh < 2; ++kh) {
      v8s af[4], bf[4];
#pragma unroll
      for (int mi = 0; mi < 4; ++mi) af[mi] = *(const v8s*)(aB + offA[mi][kh]);
#pragma unroll
      for (int ni = 0; ni < 4; ++ni) bf[ni] = *(const v8s*)(bB + offB[ni][kh]);
#pragma unroll
      for (int mi = 0; mi < 4; ++mi)
#pragma unroll
        for (int ni = 0; ni < 4; ++ni)
          acc[mi][ni] = __builtin_amdgcn_mfma_f32_16x16x32_bf16(af[mi], bf[ni], acc[mi][ni], 0, 0, 0);
    }
    __syncthreads();
  }

  float bcol[4], wcol[4];
#pragma unroll
  for (int ni = 0; ni < 4; ++ni) {
    int col = bn + wc*64 + ni*16 + fr;
    bcol[ni] = biasz[col];
    wcol[ni] = w2z[col];
  }
  float* FLp = FL2 + (size_t)blockIdx.y * Mq * Nq;
#pragma unroll
  for (int mi = 0; mi < 4; ++mi) {
#pragma unroll
    for (int reg = 0; reg < 4; ++reg) {
      float s = 0.f;
#pragma unroll
      for (int ni = 0; ni < 4; ++ni) {
        float v = acc[mi][ni][reg] + bcol[ni];
        v = v >= 0.f ? v : 0.1f * v;
        s += v * wcol[ni];
      }
#pragma unroll
      for (int off = 1; off < 16; off <<= 1)
        s += __shfl_xor(s, off, 64);
      if (fr == 0) {
        int grow = bm + wr*64 + mi*16 + fq*4 + reg;
        atomicAdd(&FLp[(size_t)grow * Nq + z], s);   // only wc=0/1 contend
      }
    }
  }
}

// full_out[m][n] = sum_bn FL2[bn][m][n] + bc2[n];
// out[b][n] = sigmoid(full_out[n*B+b][n])
__global__ void k_final(const float* __restrict__ fl2, const float* __restrict__ bc2,
                        float* __restrict__ out) {
  int i = blockIdx.x * 256 + threadIdx.x;
  int m = i >> 4, n = i & 15;
  float v = fl2[i] + fl2[(size_t)Mq*Nq + i] + fl2[2*(size_t)Mq*Nq + i]
          + fl2[3*(size_t)Mq*Nq + i] + bc2[n];
  out[Mq + i] = v;
  if (n == (m >> 10)) {
    int b = m & (Bq - 1);
    out[b * Nq + n] = 1.f / (1.f + __expf(-v));
  }
}

extern "C" void kernel_launch(void* const* d_in, const int* in_sizes, int n_in,
                              void* d_out, int out_size, void* d_ws, size_t ws_size,
                              hipStream_t stream) {
  (void)in_sizes; (void)n_in; (void)out_size; (void)ws_size;
  const float* x   = (const float*)d_in[0];
  const float* Ws1 = (const float*)d_in[1];
  const float* bs1 = (const float*)d_in[2];
  const float* Ws2 = (const float*)d_in[3];
  const float* bs2 = (const float*)d_in[4];
  const float* Wc1 = (const float*)d_in[5];
  const float* bc1 = (const float*)d_in[6];
  const float* Wc2 = (const float*)d_in[7];
  const float* bc2 = (const float*)d_in[8];

  char* ws = (char*)d_ws;
  unsigned short* Xb   = (unsigned short*)(ws);
  unsigned short* Hbuf = (unsigned short*)(ws + (size_t)16*1024*1024);
  unsigned short* Sm   = (unsigned short*)(ws + (size_t)32*1024*1024);
  unsigned short* Ws1t = (unsigned short*)(ws + (size_t)48*1024*1024);
  unsigned short* Ws2t = (unsigned short*)(ws + (size_t)48*1024*1024 + 512*1024);
  unsigned short* Wc1t = (unsigned short*)(ws + (size_t)49*1024*1024);
  float*          FL2  = (float*)         (ws + (size_t)57*1024*1024);   // 4 MB

  hipMemsetAsync(FL2, 0, (size_t)4 * Mq * Nq * sizeof(float), stream);

  k_prep<<<Bq + 18*256, 256, 0, stream>>>(x, Ws1, Ws2, Wc1, Xb, Ws1t, Ws2t, Wc1t);

  k_gemm2<<<dim3(128,2), 256, 0, stream>>>(Xb,   Ws1t, bs1, Hbuf, 0);
  k_gemm2<<<dim3(128,2), 256, 0, stream>>>(Hbuf, Ws2t, bs2, Sm,   1);
  k_headgemm<<<dim3(128,4,16), 256, 0, stream>>>(Sm, Wc1t, bc1, FL2, Wc2);

  k_final<<<(Mq*Nq)/256, 256, 0, stream>>>(FL2, bc2, (float*)d_out);
}

// Round 14
// 315.323 us; speedup vs baseline: 1.2033x; 1.2033x over previous
//
#include <hip/hip_runtime.h>
#include <hip/hip_bf16.h>
#include <stdint.h>

// Problem constants
#define Bq 1024
#define Dq 512
#define Nq 16
#define Hq 512
#define Mq (Bq*Nq)   // 16384

typedef short v8s  __attribute__((ext_vector_type(8)));
typedef float v4f  __attribute__((ext_vector_type(4)));
typedef float v16f __attribute__((ext_vector_type(16)));

typedef __attribute__((address_space(3))) unsigned int as3_u32;
typedef __attribute__((address_space(1))) const unsigned int as1_u32;

__device__ __forceinline__ unsigned short f2bf(float f) {
  union { float f; unsigned u; } v; v.f = f;
  return (unsigned short)((v.u + 0x7fffu + ((v.u >> 16) & 1u)) >> 16);
}

// Xb[b*16+n][d] = bf16(x[b][d][n])
__global__ void k_transpose_x(const float* __restrict__ x, unsigned short* __restrict__ xb) {
  __shared__ float lds[Dq][Nq + 1];
  const int b = blockIdx.x;
  const float* xi = x + (size_t)b * Dq * Nq;
  const int t = threadIdx.x;
  for (int p = 0; p < (Dq*Nq)/256; ++p) {
    int i = t + p*256;
    lds[i >> 4][i & (Nq-1)] = xi[i];
  }
  __syncthreads();
  unsigned short* o = xb + (size_t)b * Nq * Dq;
  for (int p = 0; p < (Dq*Nq)/256; ++p) {
    int i = t + p*256;
    o[i] = f2bf(lds[i & (Dq-1)][i >> 9]);   // i = n*512 + d
  }
}

// One dispatch for all weight transposes: z=0 -> Ws1, z=1 -> Ws2, z>=2 -> Wc1[z-2]
__global__ void k_transpose_w(const float* __restrict__ Ws1, const float* __restrict__ Ws2,
                              const float* __restrict__ Wc1,
                              unsigned short* __restrict__ Ws1t, unsigned short* __restrict__ Ws2t,
                              unsigned short* __restrict__ Wc1t) {
  __shared__ float tile[32][33];
  const int z = blockIdx.z;
  const float* in;
  unsigned short* out;
  if (z == 0)      { in = Ws1; out = Ws1t; }
  else if (z == 1) { in = Ws2; out = Ws2t; }
  else             { in = Wc1 + (size_t)(z-2) * 512 * 512; out = Wc1t + (size_t)(z-2) * 512 * 512; }
  const int tx = threadIdx.x, ty = threadIdx.y;  // (32,8)
  const int c0 = blockIdx.x * 32, r0 = blockIdx.y * 32;
#pragma unroll
  for (int j = 0; j < 4; ++j)
    tile[ty + j*8][tx] = in[(size_t)(r0 + ty + j*8) * 512 + c0 + tx];
  __syncthreads();
#pragma unroll
  for (int j = 0; j < 4; ++j) {
    int c = c0 + ty + j*8;   // output row (input col)
    int r = r0 + tx;         // output col (input row)
    out[(size_t)c * 512 + r] = f2bf(tile[tx][ty + j*8]);
  }
}

// ---------------------------------------------------------------------------
// Old-structure GEMM, kept for the two shared-MLP GEMMs (MODE=0 only).
// ---------------------------------------------------------------------------
template<int MODE, int BM>
__global__ __launch_bounds__(256, 2)
void k_gemm(const unsigned short* __restrict__ A,
            const unsigned short* __restrict__ Bt,
            const float* __restrict__ bias,
            void* __restrict__ out_,
            const float* __restrict__ w2,
            int permute) {
  constexpr int BN = 128, BK = 32, KD = 512;
  constexpr int NI = (BM == 256) ? 4 : 2;
  constexpr int AG = BM / 16;
  constexpr int TG = AG + BN / 16;
  __shared__ __align__(16) unsigned short As[2][BM][BK];
  __shared__ __align__(16) unsigned short Bs[2][BN][BK];

  const int t = threadIdx.x;
  const int wave = t >> 6, lane = t & 63;
  const int wr = (BM == 256) ? wave : (wave >> 1);
  const int wc = (BM == 256) ? 0    : (wave & 1);
  const int l32 = lane & 31, kh0 = lane >> 5;
  const int bm = blockIdx.x * BM, bn = blockIdx.y * BN;
  const int z = blockIdx.z;

  const unsigned short* Bz = Bt + (size_t)z * KD * 512;
  const float* biasz = bias + (size_t)z * 512;

  const int lrow = lane >> 2;
  const int lslot = lane & 3;

  auto stage = [&](int buf, int kt) {
#pragma unroll
    for (int i = wave; i < TG; i += 4) {
      const int isA = (i < AG);
      const int r0 = (isA ? i : i - AG) * 16;
      const int row = r0 + lrow;
      const int cg = lslot ^ ((row >> 1) & 3);
      const unsigned short* g = isA ? &A [(size_t)(bm + row) * KD + kt*BK + cg*8]
                                    : &Bz[(size_t)(bn + row) * KD + kt*BK + cg*8];
      as3_u32* d = isA ? (as3_u32*)&As[buf][r0][0] : (as3_u32*)&Bs[buf][r0][0];
      __builtin_amdgcn_global_load_lds((as1_u32*)g, d, 16, 0, 0);
    }
  };

  v16f acc[2][NI] = {};

  stage(0, 0);
  __syncthreads();

  for (int kt = 0; kt < KD / BK; ++kt) {
    const int cur = kt & 1;
    if (kt + 1 < KD / BK) stage(cur ^ 1, kt + 1);

    v8s af[2][2], bf[NI][2];
#pragma unroll
    for (int mi = 0; mi < 2; ++mi) {
      int ra = wr*64 + mi*32 + l32;
#pragma unroll
      for (int kh = 0; kh < 2; ++kh) {
        int c = kh*2 + kh0;
        af[mi][kh] = *(const v8s*)&As[cur][ra][(c ^ ((ra >> 1) & 3)) * 8];
      }
    }
#pragma unroll
    for (int ni = 0; ni < NI; ++ni) {
      int rb = wc*64 + ni*32 + l32;
#pragma unroll
      for (int kh = 0; kh < 2; ++kh) {
        int c = kh*2 + kh0;
        bf[ni][kh] = *(const v8s*)&Bs[cur][rb][(c ^ ((rb >> 1) & 3)) * 8];
      }
    }
#pragma unroll
    for (int kh = 0; kh < 2; ++kh)
#pragma unroll
      for (int mi = 0; mi < 2; ++mi)
#pragma unroll
        for (int ni = 0; ni < NI; ++ni)
          acc[mi][ni] = __builtin_amdgcn_mfma_f32_32x32x16_bf16(af[mi][kh], bf[ni][kh], acc[mi][ni], 0, 0, 0);
    __syncthreads();
  }

  if (MODE == 0) {
    unsigned short* O = (unsigned short*)out_;
#pragma unroll
    for (int mi = 0; mi < 2; ++mi) {
#pragma unroll
      for (int ni = 0; ni < NI; ++ni) {
        int col = bn + wc*64 + ni*32 + l32;
        float bcol = biasz[col];
#pragma unroll
        for (int reg = 0; reg < 16; ++reg) {
          int rl = (reg & 3) + 8*(reg >> 2) + 4*kh0;
          int grow = bm + wr*64 + mi*32 + rl;
          int orow = permute ? ((grow & 15) * Bq + (grow >> 4)) : grow;
          float v = acc[mi][ni][reg] + bcol;
          v = v >= 0.f ? v : 0.1f * v;
          O[(size_t)orow * 512 + col] = f2bf(v);
        }
      }
    }
  } else {
    float* FL = (float*)out_;
    const float* w2z = w2 + (size_t)z * 512;
#pragma unroll
    for (int mi = 0; mi < 2; ++mi) {
#pragma unroll
      for (int reg = 0; reg < 16; ++reg) {
        int rl = (reg & 3) + 8*(reg >> 2) + 4*kh0;
        float s = 0.f;
#pragma unroll
        for (int ni = 0; ni < NI; ++ni) {
          int col = bn + ni*32 + l32;
          float v = acc[mi][ni][reg] + biasz[col];
          v = v >= 0.f ? v : 0.1f * v;
          s += v * w2z[col];
        }
#pragma unroll
        for (int off = 1; off < 32; off <<= 1)
          s += __shfl_xor(s, off, 64);
        if (l32 == 0) {
          int grow = bm + wave*64 + mi*32 + rl;
          atomicAdd(&FL[(size_t)grow * Nq + z], s);
        }
      }
    }
  }
}

// ---------------------------------------------------------------------------
// Head-GEMM (R9, session best: 200.4us, MfmaUtil 29.6, 0 conflicts).
// 128x256 tile, 256 threads = 4 waves (2x2) of 64x128 each, acc[4][8] v4f.
// BK=32 dbuf, prefetch-before-compute, one barrier per K-step, natural
// dispatch order, 16x16x32 fragments, zero-conflict chunk-XOR swizzle.
// Plateau note (12-round ledger): conflicts, latency-cover depth, occupancy,
// barrier count, tile aspect, LDS routing, BK granularity, dispatch swizzles,
// setprio/sched_barrier/counted-vmcnt -- all individually falsified at
// ~30% MfmaUtil with no pipe >35% busy.  This is the best measured config.
// ---------------------------------------------------------------------------
__global__ __launch_bounds__(256, 2)
void k_headgemm(const unsigned short* __restrict__ A,
                const unsigned short* __restrict__ Bt,
                const float* __restrict__ bias,
                float* __restrict__ FL,
                const float* __restrict__ w2) {
  __shared__ __align__(16) unsigned short As[2][128][32];
  __shared__ __align__(16) unsigned short Bs[2][256][32];

  const int t = threadIdx.x;
  const int wave = t >> 6, lane = t & 63;
  const int wr = wave >> 1, wc = wave & 1;         // 2x2 waves of 64x128
  const int fr = lane & 15, fq = lane >> 4;

  const int bm = blockIdx.x * 128;
  const int bn = blockIdx.y * 256;
  const int z  = blockIdx.z;

  const unsigned short* Bz = Bt + (size_t)z * Dq * 512;
  const float* biasz = bias + (size_t)z * 512;
  const float* w2z   = w2   + (size_t)z * 512;

  const int sr = lane >> 2;
  const int sc = (lane & 3) ^ ((sr >> 1) & 3);
  const unsigned short* aSrc = A  + (size_t)(bm + wave*32 + sr) * Dq + sc*8;
  const unsigned short* bSrc = Bz + (size_t)(bn + wave*64 + sr) * Dq + sc*8;

  auto stage = [&](int buf, int kt) {
#pragma unroll
    for (int j = 0; j < 2; ++j)
      __builtin_amdgcn_global_load_lds((as1_u32*)(aSrc + kt*32 + (size_t)j*16*Dq),
                                       (as3_u32*)&As[buf][wave*32 + j*16][0], 16, 0, 0);
#pragma unroll
    for (int j = 0; j < 4; ++j)
      __builtin_amdgcn_global_load_lds((as1_u32*)(bSrc + kt*32 + (size_t)j*16*Dq),
                                       (as3_u32*)&Bs[buf][wave*64 + j*16][0], 16, 0, 0);
  };

  const int swz = (fq ^ ((fr >> 1) & 3)) * 16;
  int offA[4], offB[8];
#pragma unroll
  for (int mi = 0; mi < 4; ++mi) offA[mi] = (wr*64  + mi*16 + fr) * 64 + swz;
#pragma unroll
  for (int ni = 0; ni < 8; ++ni) offB[ni] = (wc*128 + ni*16 + fr) * 64 + swz;

  v4f acc[4][8] = {};

  stage(0, 0);
  __syncthreads();                 // prologue drain: tile 0 resident

  for (int kt = 0; kt < 16; ++kt) {
    const int cur = kt & 1;
    if (kt + 1 < 16) stage(cur ^ 1, kt + 1);   // prefetch flies during compute

    const char* aB = (const char*)&As[cur][0][0];
    const char* bB = (const char*)&Bs[cur][0][0];
    v8s af[4], bf[8];
#pragma unroll
    for (int mi = 0; mi < 4; ++mi) af[mi] = *(const v8s*)(aB + offA[mi]);
#pragma unroll
    for (int ni = 0; ni < 8; ++ni) bf[ni] = *(const v8s*)(bB + offB[ni]);
#pragma unroll
    for (int mi = 0; mi < 4; ++mi)
#pragma unroll
      for (int ni = 0; ni < 8; ++ni)
        acc[mi][ni] = __builtin_amdgcn_mfma_f32_16x16x32_bf16(af[mi], bf[ni], acc[mi][ni], 0, 0, 0);

    __syncthreads();               // closes reads of cur + drains prefetch
  }

  // Epilogue: lrelu + Wc2 dot over this wave's 128 cols, 16-lane reduce,
  // atomicAdd into FL[m][z].  D-frag: col=l&15, row=(l>>4)*4+reg.
  float bcol[8], wcol[8];
#pragma unroll
  for (int ni = 0; ni < 8; ++ni) {
    int col = bn + wc*128 + ni*16 + fr;
    bcol[ni] = biasz[col];
    wcol[ni] = w2z[col];
  }
#pragma unroll
  for (int mi = 0; mi < 4; ++mi) {
#pragma unroll
    for (int reg = 0; reg < 4; ++reg) {
      float s = 0.f;
#pragma unroll
      for (int ni = 0; ni < 8; ++ni) {
        float v = acc[mi][ni][reg] + bcol[ni];
        v = v >= 0.f ? v : 0.1f * v;
        s += v * wcol[ni];
      }
#pragma unroll
      for (int off = 1; off < 16; off <<= 1)
        s += __shfl_xor(s, off, 64);
      if (fr == 0) {
        int grow = bm + wr*64 + mi*16 + fq*4 + reg;
        atomicAdd(&FL[(size_t)grow * Nq + z], s);
      }
    }
  }
}

// full_out[m][n] = FL[m][n] + bc2[n]; out[b][n] = sigmoid(full_out[n*B+b][n])
__global__ void k_final(const float* __restrict__ fl, const float* __restrict__ bc2,
                        float* __restrict__ out) {
  int i = blockIdx.x * 256 + threadIdx.x;
  int m = i >> 4, n = i & 15;
  float v = fl[i] + bc2[n];
  out[Mq + i] = v;
  if (n == (m >> 10)) {
    int b = m & (Bq - 1);
    out[b * Nq + n] = 1.f / (1.f + __expf(-v));
  }
}

extern "C" void kernel_launch(void* const* d_in, const int* in_sizes, int n_in,
                              void* d_out, int out_size, void* d_ws, size_t ws_size,
                              hipStream_t stream) {
  (void)in_sizes; (void)n_in; (void)out_size; (void)ws_size;
  const float* x   = (const float*)d_in[0];
  const float* Ws1 = (const float*)d_in[1];
  const float* bs1 = (const float*)d_in[2];
  const float* Ws2 = (const float*)d_in[3];
  const float* bs2 = (const float*)d_in[4];
  const float* Wc1 = (const float*)d_in[5];
  const float* bc1 = (const float*)d_in[6];
  const float* Wc2 = (const float*)d_in[7];
  const float* bc2 = (const float*)d_in[8];

  char* ws = (char*)d_ws;
  unsigned short* Xb   = (unsigned short*)(ws);
  unsigned short* Hbuf = (unsigned short*)(ws + (size_t)16*1024*1024);
  unsigned short* Sm   = (unsigned short*)(ws + (size_t)32*1024*1024);
  unsigned short* Ws1t = (unsigned short*)(ws + (size_t)48*1024*1024);
  unsigned short* Ws2t = (unsigned short*)(ws + (size_t)48*1024*1024 + 512*1024);
  unsigned short* Wc1t = (unsigned short*)(ws + (size_t)49*1024*1024);
  float*          FL   = (float*)         (ws + (size_t)57*1024*1024);

  (void)hipMemsetAsync(FL, 0, (size_t)Mq * Nq * sizeof(float), stream);

  k_transpose_x<<<Bq, 256, 0, stream>>>(x, Xb);
  k_transpose_w<<<dim3(16,16,18), dim3(32,8), 0, stream>>>(Ws1, Ws2, Wc1, Ws1t, Ws2t, Wc1t);

  // shared MLP: H = lrelu(Xb@Ws1+bs1); Sm = lrelu(H@Ws2+bs2) in m = n*B+b row order
  k_gemm<0,128><<<dim3(128,4,1), 256, 0, stream>>>(Xb,   Ws1t, bs1, Hbuf, nullptr, 0);
  k_gemm<0,128><<<dim3(128,4,1), 256, 0, stream>>>(Hbuf, Ws2t, bs2, Sm,   nullptr, 1);
  // fused per-head GEMM + H-reduction into FL (R9 verbatim, session best)
  k_headgemm<<<dim3(128,2,16), 256, 0, stream>>>(Sm, Wc1t, bc1, FL, Wc2);

  k_final<<<(Mq*Nq)/256, 256, 0, stream>>>(FL, bc2, (float*)d_out);
}